// Round 8
// baseline (616.897 us; speedup 1.0000x reference)
//
#include <hip/hip_runtime.h>
#include <hip/hip_bf16.h>
#include <math.h>

// IntegralTransform, j-sorted edge processing.
// Pipeline (all on stream): k_zero (out + cnt) -> k_hist (count j) ->
// k_scan (exclusive prefix, in-place cursors) -> k_scatter (pairs[pos] =
// {j, e}) -> it_prep (fused node table T[j] = [A(64 bf16) | g(32 bf16)],
// A[j] = y_j*W1[0:3] + fy_j*W1[6:38], g[j] = w_j*fy_j) -> it_main.
// it_main walks edges in j-order: mean multiplicity E/N = 32 means a
// 32-edge tile spans ~1-2 distinct j -> T gathers are L2-resident
// (~10 MB total demand vs 410 MB random in rounds 4-7, which were all
// pinned at the ~3.5 TB/s random-line service ceiling). B[i] from y[i]
// (0.6 MB, L2-resident) distributed by shfl. Segment-sum becomes
// global_atomic_add_f32 scatter into zeroed out (i's random -> ~no
// contention, 64-B coalesced bursts).

typedef __attribute__((ext_vector_type(8))) short short8;
typedef __attribute__((ext_vector_type(4))) float floatx4;

__device__ __forceinline__ unsigned short bf16rne(float f) {
    unsigned int u = __float_as_uint(f);
    u += 0x7fffu + ((u >> 16) & 1u);
    return (unsigned short)(u >> 16);
}
__device__ __forceinline__ unsigned int pk2(float a, float b) {
    union { __hip_bfloat162 h; unsigned int u; } cv;
    cv.h = __float22bfloat162_rn(make_float2(a, b));
    return cv.u;
}
__device__ __forceinline__ float bf16f(unsigned short u) {
    return __uint_as_float(((unsigned int)u) << 16);
}
__device__ __forceinline__ float blo(unsigned int u) { return __uint_as_float(u << 16); }
__device__ __forceinline__ float bhi(unsigned int u) { return __uint_as_float(u & 0xffff0000u); }
// sigmoid-form gelu: x/(1+exp(-1.702x)); |err| <= ~0.02, threshold 3.1e-1.
__device__ __forceinline__ float gelu_fast(float x) {
    float e = __expf(-1.702f * x);
    return x * __builtin_amdgcn_rcpf(1.0f + e);
}

#define MFMA16(a, b, c) __builtin_amdgcn_mfma_f32_16x16x32_bf16(a, b, c, 0, 0, 0)

// ---------------- sort machinery ----------------
__global__ __launch_bounds__(256) void k_zero(float* __restrict__ out, int nout,
                                              int* __restrict__ cnt, int ncnt)
{
    int idx = blockIdx.x * 256 + threadIdx.x;
    if (idx < nout) out[idx] = 0.f;
    if (idx < ncnt) cnt[idx] = 0;
}

__global__ __launch_bounds__(256) void k_hist(const int* __restrict__ nbr,
                                              int* __restrict__ cnt, int E)
{
    int e = blockIdx.x * 256 + threadIdx.x;
    if (e < E) atomicAdd(cnt + nbr[e], 1);
}

__global__ __launch_bounds__(1024) void k_scan(int* __restrict__ cnt, int n)
{
    __shared__ int part[1024];
    const int tid = threadIdx.x;
    const int chunk = (n + 1023) >> 10;
    const int lo = tid * chunk;
    const int hi = min(lo + chunk, n);
    int s = 0;
    for (int k = lo; k < hi; ++k) s += cnt[k];
    part[tid] = s;
    __syncthreads();
    for (int off = 1; off < 1024; off <<= 1) {
        int v = (tid >= off) ? part[tid - off] : 0;
        __syncthreads();
        part[tid] += v;
        __syncthreads();
    }
    int run = (tid > 0) ? part[tid - 1] : 0;
    for (int k = lo; k < hi; ++k) { int c = cnt[k]; cnt[k] = run; run += c; }
}

__global__ __launch_bounds__(256) void k_scatter(const int* __restrict__ nbr,
                                                 int* __restrict__ cur,
                                                 int2* __restrict__ pairs, int E)
{
    int e = blockIdx.x * 256 + threadIdx.x;
    if (e >= E) return;
    int j = nbr[e];
    int pos = atomicAdd(cur + j, 1);
    pairs[pos] = make_int2(j, e);
}

// ---------------- prep: fused T[N][96] bf16 ----------------
__global__ __launch_bounds__(256) void it_prep(
    const float* __restrict__ y, const float* __restrict__ fy,
    const float* __restrict__ wts, const float* __restrict__ W1,
    unsigned short* __restrict__ T, int n)
{
    const int j = blockIdx.x * 4 + (threadIdx.x >> 6);   // 1 wave per node
    const int l = threadIdx.x & 63;
    if (j >= n) return;
    const float* fyr = fy + (long)j * 32;
    float acc = y[3 * j] * W1[l];
    acc = fmaf(y[3 * j + 1], W1[64 + l], acc);
    acc = fmaf(y[3 * j + 2], W1[128 + l], acc);
    #pragma unroll
    for (int c = 0; c < 32; ++c)
        acc = fmaf(fyr[c], W1[(6 + c) * 64 + l], acc);
    unsigned short* row = T + (long)j * 96;
    row[l] = bf16rne(acc);
    if (l < 32) row[64 + l] = bf16rne(wts[j] * fyr[l]);
}

// ---------------- main kernel: j-sorted tiles of 32 edges ----------------
__global__ __launch_bounds__(256, 4) void it_main(
    const unsigned short* __restrict__ T,
    const float* __restrict__ y,
    const float* __restrict__ W1, const float* __restrict__ b1,
    const float* __restrict__ W2, const float* __restrict__ b2,
    const float* __restrict__ W3, const float* __restrict__ b3,
    const int2* __restrict__ pairs,
    float* __restrict__ out, int E)
{
    __shared__ unsigned short ldsB[4][32][72];   // h2 round trip
    __shared__ unsigned short ldsG[4][32][32];   // g stage

    const int lane = threadIdx.x & 63;
    const int wv   = threadIdx.x >> 6;
    const int quad = lane >> 4;
    const int c16  = lane & 15;
    const int l31  = lane & 31;
    const int wgid   = blockIdx.x * 4 + wv;
    const int nwaves = gridDim.x * 4;

    // ---- per-lane B-slice of W1 rows 3..5 + b1: channel = kb*32 + 8*quad + jj ----
    float wb0[2][8], wb1[2][8], wb2[2][8], b1e[2][8];
    #pragma unroll
    for (int kb = 0; kb < 2; ++kb)
        #pragma unroll
        for (int jj = 0; jj < 8; ++jj) {
            int l = kb * 32 + quad * 8 + jj;
            wb0[kb][jj] = W1[3 * 64 + l];
            wb1[kb][jj] = W1[4 * 64 + l];
            wb2[kb][jj] = W1[5 * 64 + l];
            b1e[kb][jj] = b1[l];
        }

    // ---- W2 fragments (natural k order) ----
    short8 w2f[2][4], w3f[2][2];
    #pragma unroll
    for (int kb = 0; kb < 2; ++kb)
        #pragma unroll
        for (int nb = 0; nb < 4; ++nb)
            #pragma unroll
            for (int jj = 0; jj < 8; ++jj) {
                int k = kb * 32 + quad * 8 + jj;
                w2f[kb][nb][jj] = (short)bf16rne(W2[k * 64 + nb * 16 + c16]);
            }
    // ---- W3 fragments (k un-permutes h2's col-permuted store) ----
    #pragma unroll
    for (int kb = 0; kb < 2; ++kb)
        #pragma unroll
        for (int nb = 0; nb < 2; ++nb)
            #pragma unroll
            for (int jj = 0; jj < 8; ++jj) {
                int kp = kb * 32 + quad * 8 + jj;
                int kl = (kp & 3) * 16 + (kp >> 2);     // logical h2 channel
                w3f[kb][nb][jj] = (short)bf16rne(W3[kl * 32 + nb * 16 + c16]);
            }
    float b2v[4], b3v0, b3v1;
    #pragma unroll
    for (int nb = 0; nb < 4; ++nb) b2v[nb] = b2[nb * 16 + c16];
    b3v0 = b3[c16]; b3v1 = b3[16 + c16];

    unsigned short (*bufB)[72] = ldsB[wv];
    unsigned short (*bufG)[32] = ldsG[wv];

    const floatx4 fz = {0.f, 0.f, 0.f, 0.f};
    const int ntiles = E >> 5;

    for (int q = wgid; q < ntiles; q += nwaves) {
        // ---- load this tile's 32 sorted (j, e) pairs ----
        int2 pr = pairs[(q << 5) + l31];
        const int jl = pr.x;
        const int il = pr.y >> 5;              // owner point of edge (K=32)
        float y0 = y[3 * il], y1 = y[3 * il + 1], y2 = y[3 * il + 2];

        // ---- gather T rows (j-sorted -> L2 hits), build h1 A-frags ----
        short8 af[2][2];
        #pragma unroll
        for (int t = 0; t < 2; ++t) {
            const int src = t * 16 + c16;
            const int jt  = __shfl(jl, src, 64);
            const float yi0 = __shfl(y0, src, 64);
            const float yi1 = __shfl(y1, src, 64);
            const float yi2 = __shfl(y2, src, 64);
            const uint4* ap = (const uint4*)(T + (long)jt * 96 + quad * 8);
            uint4 a0 = ap[0];                   // A channels kb=0
            uint4 a1 = ap[4];                   // A channels kb=1
            uint4 gv = ap[8];                   // g channels
            *(uint4*)&bufG[t * 16 + c16][quad * 8] = gv;
            #pragma unroll
            for (int kb = 0; kb < 2; ++kb) {
                float Bv[8];
                #pragma unroll
                for (int jj = 0; jj < 8; ++jj)
                    Bv[jj] = fmaf(yi2, wb2[kb][jj],
                             fmaf(yi1, wb1[kb][jj],
                             fmaf(yi0, wb0[kb][jj], b1e[kb][jj])));
                uint4 av = kb ? a1 : a0;
                float z0 = gelu_fast(blo(av.x) + Bv[0]);
                float z1 = gelu_fast(bhi(av.x) + Bv[1]);
                float z2 = gelu_fast(blo(av.y) + Bv[2]);
                float z3 = gelu_fast(bhi(av.y) + Bv[3]);
                float z4 = gelu_fast(blo(av.z) + Bv[4]);
                float z5 = gelu_fast(bhi(av.z) + Bv[5]);
                float z6 = gelu_fast(blo(av.w) + Bv[6]);
                float z7 = gelu_fast(bhi(av.w) + Bv[7]);
                union { uint4 u; short8 s; } cv;
                cv.u = make_uint4(pk2(z0, z1), pk2(z2, z3), pk2(z4, z5), pk2(z6, z7));
                af[t][kb] = cv.s;
            }
        }

        // ---- layer 2 ----
        floatx4 acc[2][4];
        #pragma unroll
        for (int t = 0; t < 2; ++t)
            #pragma unroll
            for (int nb = 0; nb < 4; ++nb) {
                acc[t][nb] = MFMA16(af[t][0], w2f[0][nb], fz);
                acc[t][nb] = MFMA16(af[t][1], w2f[1][nb], acc[t][nb]);
            }
        #pragma unroll
        for (int t = 0; t < 2; ++t)
            #pragma unroll
            for (int r = 0; r < 4; ++r) {
                float g0 = gelu_fast(acc[t][0][r] + b2v[0]);
                float g1 = gelu_fast(acc[t][1][r] + b2v[1]);
                float g2 = gelu_fast(acc[t][2][r] + b2v[2]);
                float g3 = gelu_fast(acc[t][3][r] + b2v[3]);
                *(uint2*)&bufB[t * 16 + quad * 4 + r][4 * c16] =
                    make_uint2(pk2(g0, g1), pk2(g2, g3));
            }

        // ---- layer 3 ----
        short8 h0[2], h1[2];
        #pragma unroll
        for (int t = 0; t < 2; ++t) {
            const int arow = t * 16 + c16;
            h0[t] = *(const short8*)&bufB[arow][quad * 8];
            h1[t] = *(const short8*)&bufB[arow][32 + quad * 8];
        }
        floatx4 o[2][2];
        #pragma unroll
        for (int t = 0; t < 2; ++t)
            #pragma unroll
            for (int nb = 0; nb < 2; ++nb) {
                o[t][nb] = MFMA16(h0[t], w3f[0][nb], fz);
                o[t][nb] = MFMA16(h1[t], w3f[1][nb], o[t][nb]);
            }

        // ---- epilogue: (o + b3) * g[j], atomic scatter to out[i] ----
        #pragma unroll
        for (int t = 0; t < 2; ++t)
            #pragma unroll
            for (int r = 0; r < 4; ++r) {
                const int orow = t * 16 + quad * 4 + r;
                const int ie   = __shfl(il, orow, 64);
                float ga = bf16f(bufG[orow][c16]);
                float gb = bf16f(bufG[orow][16 + c16]);
                atomicAdd(out + ie * 32 + c16,      (o[t][0][r] + b3v0) * ga);
                atomicAdd(out + ie * 32 + 16 + c16, (o[t][1][r] + b3v1) * gb);
            }
    }
}

extern "C" void kernel_launch(void* const* d_in, const int* in_sizes, int n_in,
                              void* d_out, int out_size, void* d_ws, size_t ws_size,
                              hipStream_t stream) {
    const float* y  = (const float*)d_in[0];
    const float* fy = (const float*)d_in[1];
    const float* wt = (const float*)d_in[2];
    const float* W1 = (const float*)d_in[3];
    const float* b1 = (const float*)d_in[4];
    const float* W2 = (const float*)d_in[5];
    const float* b2 = (const float*)d_in[6];
    const float* W3 = (const float*)d_in[7];
    const float* b3 = (const float*)d_in[8];
    const int* nbr  = (const int*)d_in[9];
    const int E = in_sizes[9];
    const int N = in_sizes[0] / 3;        // nodes
    float* out = (float*)d_out;

    // ws: T (N*192 B) | pairs (E*8 B) | cnt (N*4 B)   -- ~22.6 MB total
    unsigned short* T = (unsigned short*)d_ws;
    int2* pairs = (int2*)((char*)d_ws + (size_t)N * 192);
    int* cnt    = (int*)((char*)d_ws + (size_t)N * 192 + (size_t)E * 8);

    const int zmax = (out_size > N) ? out_size : N;
    hipLaunchKernelGGL(k_zero, dim3((zmax + 255) / 256), dim3(256), 0, stream,
                       out, out_size, cnt, N);
    hipLaunchKernelGGL(k_hist, dim3((E + 255) / 256), dim3(256), 0, stream,
                       nbr, cnt, E);
    hipLaunchKernelGGL(k_scan, dim3(1), dim3(1024), 0, stream, cnt, N);
    hipLaunchKernelGGL(k_scatter, dim3((E + 255) / 256), dim3(256), 0, stream,
                       nbr, cnt, pairs, E);
    hipLaunchKernelGGL(it_prep, dim3((N + 3) / 4), dim3(256), 0, stream,
                       y, fy, wt, W1, T, N);
    // persistent: 1024 blocks x 4 waves (4 blocks/CU resident)
    hipLaunchKernelGGL(it_main, dim3(1024), dim3(256), 0, stream,
                       T, y, W1, b1, W2, b2, W3, b3, pairs, out, E);
}